// Round 5
// baseline (190.723 us; speedup 1.0000x reference)
//
#include <hip/hip_runtime.h>

// FusedMHC: per 8x8 block, M = exp(x), then 5 Sinkhorn-Knopp iterations.
// 4 threads per matrix; each thread owns 2 rows (16 floats) in registers.
//
// Scale-factor formulation (no in-place rescaling of M):
//   out[i][j] = M0[i][j] * r_i * c_j,  c_j init 1,
//   iter: r_i = 1/sum_j M0[i][j]*c_j ;  c_j = 1/sum_i M0[i][j]*r_i
// Identical by induction to alternating row/col normalization, but the
// per-iteration VALU cost drops from 70 to 48 insts/thread (M0 is never
// touched) -> VALU pipe (~600 cy/wave) drops below memory (~800 cy/wave).
//
// I/O staged through LDS (coalesced float4 streams, XOR swizzle, conflict
// free); col sums via DPP quad_perm butterfly (no DS pipe, no barrier).
// 64 B LDS/thread -> occupancy capped by wave limit: 8 blocks/CU, 32 waves/CU.

constexpr int MHC_ITERS = 5;
constexpr int THREADS = 256;
constexpr int MATS_PER_BLOCK = THREADS / 4;        // 64 matrices/block
constexpr int F4_PER_BLOCK = MATS_PER_BLOCK * 16;  // 1024 float4 = 16 KB

// dpp_ctrl must be a compile-time constant -> template parameter.
template <int CTRL>
__device__ __forceinline__ float quad_xor_add(float x) {
    int peer = __builtin_amdgcn_update_dpp(0, __float_as_int(x), CTRL, 0xF, 0xF, true);
    return x + __int_as_float(peer);
}

__global__ __launch_bounds__(THREADS)
void fused_mhc_kernel(const float* __restrict__ x, float* __restrict__ out) {
    __shared__ float4 lds[F4_PER_BLOCK];

    const int t = threadIdx.x;
    const size_t base = (size_t)blockIdx.x * F4_PER_BLOCK;
    const float4* __restrict__ src = reinterpret_cast<const float4*>(x) + base;
    float4* __restrict__ dst = reinterpret_cast<float4*>(out) + base;

    // ---- Stage in: coalesced global -> swizzled LDS (4 passes) ----
    #pragma unroll
    for (int p = 0; p < 4; ++p) {
        int g = p * THREADS + t;
        lds[g ^ ((g >> 4) & 15)] = src[g];
    }
    __syncthreads();

    // ---- Gather: thread (m,h) owns rows 2h, 2h+1 of local matrix m ----
    const int m = t >> 2;
    const int h = t & 3;
    const int swz = m & 15;

    float M[16];  // M[0..7] = row 2h, M[8..15] = row 2h+1
    #pragma unroll
    for (int j = 0; j < 4; ++j) {
        float4 v = lds[(m * 16 + h * 4 + j) ^ swz];
        M[j * 4 + 0] = v.x;
        M[j * 4 + 1] = v.y;
        M[j * 4 + 2] = v.z;
        M[j * 4 + 3] = v.w;
    }

    #pragma unroll
    for (int i = 0; i < 16; ++i) M[i] = __expf(M[i]);

    // ---- Sinkhorn via row/col scale factors; M stays untouched ----
    float c[8];
    #pragma unroll
    for (int j = 0; j < 8; ++j) c[j] = 1.0f;

    float r0, r1;
    #pragma unroll
    for (int it = 0; it < MHC_ITERS; ++it) {
        // Row phase: r_i = 1 / sum_j M[i][j]*c_j (both rows thread-local).
        float d0 = M[0] * c[0];
        float d1 = M[8] * c[0];
        #pragma unroll
        for (int j = 1; j < 8; ++j) {
            d0 = fmaf(M[j], c[j], d0);
            d1 = fmaf(M[8 + j], c[j], d1);
        }
        r0 = __builtin_amdgcn_rcpf(d0);
        r1 = __builtin_amdgcn_rcpf(d1);

        // Col phase: c_j = 1 / sum_i M[i][j]*r_i (quad butterfly via DPP).
        // 0xB1 = quad_perm [1,0,3,2] (xor 1), 0x4E = quad_perm [2,3,0,1] (xor 2).
        #pragma unroll
        for (int j = 0; j < 8; ++j) {
            float p = fmaf(M[8 + j], r1, M[j] * r0);
            p = quad_xor_add<0xB1>(p);
            p = quad_xor_add<0x4E>(p);
            c[j] = __builtin_amdgcn_rcpf(p);
        }
    }

    // ---- Apply scales and scatter back to own (private) swizzled slots ----
    #pragma unroll
    for (int j = 0; j < 8; ++j) {
        M[j] *= r0 * c[j];
        M[8 + j] *= r1 * c[j];
    }

    #pragma unroll
    for (int j = 0; j < 4; ++j) {
        float4 v;
        v.x = M[j * 4 + 0];
        v.y = M[j * 4 + 1];
        v.z = M[j * 4 + 2];
        v.w = M[j * 4 + 3];
        lds[(m * 16 + h * 4 + j) ^ swz] = v;
    }
    __syncthreads();

    // ---- Stage out: swizzled LDS -> coalesced global ----
    #pragma unroll
    for (int p = 0; p < 4; ++p) {
        int g = p * THREADS + t;
        dst[g] = lds[g ^ ((g >> 4) & 15)];
    }
}

extern "C" void kernel_launch(void* const* d_in, const int* in_sizes, int n_in,
                              void* d_out, int out_size, void* d_ws, size_t ws_size,
                              hipStream_t stream) {
    const float* x = (const float*)d_in[0];
    float* out = (float*)d_out;

    const int nmat = in_sizes[0] / 64;                // 8x8 matrices
    const int blocks = nmat / MATS_PER_BLOCK;         // 2,097,152 / 64 = 32768

    fused_mhc_kernel<<<blocks, THREADS, 0, stream>>>(x, out);
}